// Round 4
// baseline (962.075 us; speedup 1.0000x reference)
//
#include <hip/hip_runtime.h>
#include <cstdint>
#include <cstddef>

typedef unsigned short u16;
typedef unsigned int   u32;

using short8 = __attribute__((ext_vector_type(8))) short;
using f32x4  = __attribute__((ext_vector_type(4))) float;

#define M_TOK 32768
#define E_DIM 1024
#define NQKV  3072

__device__ __forceinline__ u16 f2bf(float f) {
  u32 u = __float_as_uint(f);
  u += 0x7FFFu + ((u >> 16) & 1u);
  return (u16)(u >> 16);
}
__device__ __forceinline__ float bf2f(u16 v) {
  return __uint_as_float((u32)v << 16);
}
__device__ __forceinline__ u32 pack2(float a, float b) {
  return (u32)f2bf(a) | ((u32)f2bf(b) << 16);
}

__device__ __forceinline__ void gl_lds16(const void* g, void* l) {
  __builtin_amdgcn_global_load_lds(
      (const __attribute__((address_space(1))) u32*)g,
      (__attribute__((address_space(3))) u32*)l, 16, 0, 0);
}

// ---------------- combined cast: x + all weights + qkv bias ----------------
__global__ __launch_bounds__(256) void cast_all_k(
    const float4* __restrict__ x,
    const float4* __restrict__ qkw, const float4* __restrict__ vw,
    const float4* __restrict__ pw,  const float4* __restrict__ fw,
    const float4* __restrict__ qkb, const float4* __restrict__ vb,
    uint2* __restrict__ xb,
    uint2* __restrict__ wqkv, uint2* __restrict__ wproj, uint2* __restrict__ wff,
    float4* __restrict__ qkvbias) {
  const int gid = blockIdx.x * 256 + threadIdx.x;   // 9,699,328 total
  if (gid < 8388608) {
    const float4 v = x[gid];
    xb[gid] = make_uint2(pack2(v.x, v.y), pack2(v.z, v.w));
    return;
  }
  const int w = gid - 8388608;                      // [0, 1,310,720)
  float4 v; uint2* dst; int di;
  if (w < 524288)        { v = qkw[w];           dst = wqkv;  di = w; }
  else if (w < 786432)   { v = vw[w - 524288];   dst = wqkv;  di = w; }
  else if (w < 1048576)  { v = pw[w - 786432];   dst = wproj; di = w - 786432; }
  else                   { v = fw[w - 1048576];  dst = wff;   di = w - 1048576; }
  dst[di] = make_uint2(pack2(v.x, v.y), pack2(v.z, v.w));
  if (w < 768) qkvbias[w] = (w < 512) ? qkb[w] : vb[w - 512];
}

// ---------------- GEMM: C[M,N] = A[M,K] @ Bw[N,K]^T (+bias, +epilogue) ----------------
// MODE 0: C=bf16(acc+bias)                 (qkv)
// MODE 1: C=bf16(acc+bias+xres)            (proj + residual, xres bf16)
// MODE 2: C=bf16(gelu(acc+bias)+xres)      (ff + gelu + residual, xres bf16)
//
// 256x256 tile, 8-phase schedule (T3+T4 counted vmcnt + T5 setprio),
// 512 threads = 8 waves (2M x 4N), per-wave output 128x64, BK=64,
// LDS 128 KiB = 2 dbuf x (A 256x64 + B 256x64) bf16.
// Chunk-XOR swizzle (pre-swizzled global source, linear LDS dest, XOR'd read).
//
// R3 counters: phase time 1594 cyc == memory service time for 16KB/CU/phase;
// default block->XCD round-robin spread A-panel sharers across XCDs (FETCH
// 339MB vs 70 ideal). R4 fix: XCD swizzle, row-tile-fastest within XCD so
// each XCD keeps ONE B-panel L2-resident and streams A-panels from L3.
//
// vmcnt ledger: prologue issues 12 loads/thread, each phase-d vmcnt(4)
// has 12 outstanding and drains the oldest 8 (= the complete next tile),
// leaving 4 (the following tile's A-halves) in flight. Never drains to 0.
template<int MODE>
__global__ __launch_bounds__(512, 2)
void gemm_bt(const u16* __restrict__ A, const u16* __restrict__ Bw,
             const float* __restrict__ bias, const u16* __restrict__ xres,
             u16* __restrict__ C, int M, int N, int K) {
  __shared__ __align__(16) u16 As[2][256 * 64];
  __shared__ __align__(16) u16 Bs[2][256 * 64];
  const int tid  = threadIdx.x;
  const int lane = tid & 63;
  const int wave = tid >> 6;
  const int wm = wave & 1;       // 2 waves in M
  const int wn = wave >> 1;      // 4 waves in N
  const int quad = lane >> 4;
  const int l15  = lane & 15;

  // ---- XCD-aware tile remap (T1) ----
  // HW round-robins consecutive flat ids over 8 XCDs. swz = (bid&7)*q + bid>>3
  // gives XCD x the contiguous swz range [x*q,(x+1)*q)  (bijective: nwg%8==0).
  // Decode row-tile FASTEST: each XCD sweeps all M-tiles for ~constant col
  // -> B-panel (512KB) stays resident in that XCD's L2; A streams from L3.
  const int bid  = blockIdx.y * gridDim.x + blockIdx.x;
  const int nwg  = gridDim.x * gridDim.y;         // 1536 (qkv) / 512 (proj,ff)
  const int q8   = nwg >> 3;
  const int swz  = (bid & 7) * q8 + (bid >> 3);
  const int tm   = swz & 127;                     // M/256 = 128 row-tiles always
  const int tn   = swz >> 7;
  const int row0 = tm << 8;
  const int col0 = tn << 8;

  f32x4 acc[8][4];
  #pragma unroll
  for (int i = 0; i < 8; ++i)
    #pragma unroll
    for (int j = 0; j < 4; ++j)
      acc[i][j] = (f32x4){0.f, 0.f, 0.f, 0.f};

  // --- staging constants (per-thread) ---
  const int rsub = tid >> 3;     // 0..63: row within a 64-row DMA slab
  const int kch  = tid & 7;      // LDS k-chunk slot this thread fills
  // --- read constants ---
  const int ck0 = quad ^ (l15 & 7);        // kk=0 swizzled chunk
  const int ck1 = (4 + quad) ^ (l15 & 7);  // kk=1 swizzled chunk
  const int mB = wm * 128 + l15;           // A row base (+h*64+i*16)
  const int nB = wn * 64 + l15;            // B row base (+j*16)

  // stage rows [half*128, half*128+128) of one K-tile of src into ldsTile
  auto STAGE_HALF = [&](const u16* __restrict__ src, int growbase, int kt,
                        u16* ldsTile, int half) {
    const int kel = kt << 6;
    #pragma unroll
    for (int c = 0; c < 2; ++c) {
      const int rl = c * 64 + rsub;                       // row within half
      const u16* g = src + (size_t)(growbase + half * 128 + rl) * K
                         + kel + ((kch ^ (rl & 7)) << 3); // pre-swizzled source
      gl_lds16(g, ldsTile + (size_t)((half << 10) + (c << 9) + (wave << 6)) * 8);
    }
  };

  auto LDA4 = [&](short8 (&dst)[4][2], const u16* tile, int hh) {
    #pragma unroll
    for (int i = 0; i < 4; ++i) {
      const int m = mB + hh * 64 + i * 16;
      dst[i][0] = *(const short8*)(tile + m * 64 + ck0 * 8);
      dst[i][1] = *(const short8*)(tile + m * 64 + ck1 * 8);
    }
  };
  auto LDB2 = [&](short8 (&dst)[2][2], const u16* tile, int jj) {
    #pragma unroll
    for (int j = 0; j < 2; ++j) {
      const int n = nB + (jj + j) * 16;
      dst[j][0] = *(const short8*)(tile + n * 64 + ck0 * 8);
      dst[j][1] = *(const short8*)(tile + n * 64 + ck1 * 8);
    }
  };
  auto QUAD = [&](short8 (&af)[4][2], short8 (&bf)[2][2], int i0, int j0) {
    #pragma unroll
    for (int kk = 0; kk < 2; ++kk)
      #pragma unroll
      for (int i = 0; i < 4; ++i)
        #pragma unroll
        for (int j = 0; j < 2; ++j)
          acc[i0 + i][j0 + j] = __builtin_amdgcn_mfma_f32_16x16x32_bf16(
              af[i][kk], bf[j][kk], acc[i0 + i][j0 + j], 0, 0, 0);
  };

  const int NT = K >> 6;        // K-tiles (16 for K=1024)
  const int NITER = NT >> 1;

  // ---- prologue: tile0 -> buf0 (4 half-tiles), tile1 A-halves -> buf1 ----
  STAGE_HALF(A,  row0, 0, As[0], 0);
  STAGE_HALF(A,  row0, 0, As[0], 1);
  STAGE_HALF(Bw, col0, 0, Bs[0], 0);
  STAGE_HALF(Bw, col0, 0, Bs[0], 1);
  STAGE_HALF(A,  row0, 1, As[1], 0);
  STAGE_HALF(A,  row0, 1, As[1], 1);
  asm volatile("s_waitcnt vmcnt(4)" ::: "memory");
  __builtin_amdgcn_s_barrier();
  __builtin_amdgcn_sched_barrier(0);

  short8 aLo[4][2], aHi[4][2], bLo[2][2], bHi[2][2];

  for (int it = 0; it < NITER; ++it) {
    #pragma unroll
    for (int h = 0; h < 2; ++h) {
      const int tB = 2 * it + h + 1;           // B-halves of this tile -> buf[h^1]
      const int tA = 2 * it + h + 2;           // A-halves of this tile -> buf[h]
      const int ktB = (tB >= NT) ? tB - NT : tB;   // wrap on final iter (harmless refetch)
      const int ktA = (tA >= NT) ? tA - NT : tA;
      const u16* AsR = As[h];
      const u16* BsR = Bs[h];
      u16* BsW = Bs[h ^ 1];
      u16* AsW = As[h];

      // ---- phase a ----
      LDA4(aLo, AsR, 0);
      LDB2(bLo, BsR, 0);
      STAGE_HALF(Bw, col0, ktB, BsW, 0);
      __builtin_amdgcn_s_barrier();
      asm volatile("s_waitcnt lgkmcnt(0)" ::: "memory");
      __builtin_amdgcn_sched_barrier(0);
      __builtin_amdgcn_s_setprio(1);
      QUAD(aLo, bLo, 0, 0);
      __builtin_amdgcn_s_setprio(0);
      __builtin_amdgcn_s_barrier();
      __builtin_amdgcn_sched_barrier(0);

      // ---- phase b ----
      LDA4(aHi, AsR, 1);
      STAGE_HALF(Bw, col0, ktB, BsW, 1);
      __builtin_amdgcn_s_barrier();
      asm volatile("s_waitcnt lgkmcnt(0)" ::: "memory");
      __builtin_amdgcn_sched_barrier(0);
      __builtin_amdgcn_s_setprio(1);
      QUAD(aHi, bLo, 4, 0);
      __builtin_amdgcn_s_setprio(0);
      __builtin_amdgcn_s_barrier();
      __builtin_amdgcn_sched_barrier(0);

      // ---- phase c ----
      LDB2(bHi, BsR, 2);
      STAGE_HALF(A, row0, ktA, AsW, 0);
      __builtin_amdgcn_s_barrier();
      asm volatile("s_waitcnt lgkmcnt(0)" ::: "memory");
      __builtin_amdgcn_sched_barrier(0);
      __builtin_amdgcn_s_setprio(1);
      QUAD(aLo, bHi, 0, 2);
      __builtin_amdgcn_s_setprio(0);
      __builtin_amdgcn_s_barrier();
      __builtin_amdgcn_sched_barrier(0);

      // ---- phase d ----
      STAGE_HALF(A, row0, ktA, AsW, 1);
      __builtin_amdgcn_s_barrier();
      asm volatile("s_waitcnt lgkmcnt(0)" ::: "memory");
      __builtin_amdgcn_sched_barrier(0);
      __builtin_amdgcn_s_setprio(1);
      QUAD(aHi, bHi, 4, 2);
      __builtin_amdgcn_s_setprio(0);
      asm volatile("s_waitcnt vmcnt(4)" ::: "memory");  // counted: next tile landed, 4 in flight
      __builtin_amdgcn_s_barrier();
      __builtin_amdgcn_sched_barrier(0);
    }
  }
  asm volatile("s_waitcnt vmcnt(0)" ::: "memory");

  // ---- epilogue ----
  #pragma unroll
  for (int j = 0; j < 4; ++j) {
    const int col = col0 + wn * 64 + j * 16 + l15;
    const float bj = bias[col];
    #pragma unroll
    for (int ai = 0; ai < 8; ++ai) {
      const int rowb = row0 + wm * 128 + ai * 16 + quad * 4;
      #pragma unroll
      for (int r = 0; r < 4; ++r) {
        const int row = rowb + r;
        float v = acc[ai][j][r] + bj;
        if (MODE == 1) {
          v += bf2f(xres[(size_t)row * N + col]);
        } else if (MODE == 2) {
          v = 0.5f * v * (1.0f + erff(v * 0.70710678118654752f))
              + bf2f(xres[(size_t)row * N + col]);
        }
        C[(size_t)row * N + col] = f2bf(v);
      }
    }
  }
}

// ---------------- per-token head-mixing attention (MFMA, 1 wave = 1 token) ----------------
__global__ __launch_bounds__(256)
void attn_k(const u16* __restrict__ qkv, u16* __restrict__ ao) {
  __shared__ __align__(16) u16 pb[4][256];
  const int tid  = threadIdx.x;
  const int wave = tid >> 6;
  const int lane = tid & 63;
  const int quad = lane >> 4;
  const int l15  = lane & 15;
  const int t = blockIdx.x * 4 + wave;
  const u16* base = qkv + (size_t)t * 3072;
  const u16* qb = base;
  const u16* kb = base + 1024;
  const u16* vb = base + 2048;

  // ---- QK^T ----
  const int fo = l15 * 64 + quad * 8;          // frag: m/n = l15, k = quad*8+j
  const short8 a0 = *(const short8*)(qb + fo);
  const short8 a1 = *(const short8*)(qb + fo + 32);
  const short8 b0 = *(const short8*)(kb + fo);
  const short8 b1 = *(const short8*)(kb + fo + 32);
  f32x4 s = (f32x4){0.f, 0.f, 0.f, 0.f};
  s = __builtin_amdgcn_mfma_f32_16x16x32_bf16(a0, b0, s, 0, 0, 0);
  s = __builtin_amdgcn_mfma_f32_16x16x32_bf16(a1, b1, s, 0, 0, 0);
  // lane holds S[h=quad*4+r][g=l15]

  // ---- softmax over g (16-lane groups share quad) ----
  float rinv[4];
  float ev[4];
  #pragma unroll
  for (int r = 0; r < 4; ++r) {
    float sv = s[r] * 0.125f;
    float m = sv;
    m = fmaxf(m, __shfl_xor(m, 1));
    m = fmaxf(m, __shfl_xor(m, 2));
    m = fmaxf(m, __shfl_xor(m, 4));
    m = fmaxf(m, __shfl_xor(m, 8));
    const float e = __expf(sv - m);
    float sm = e;
    sm += __shfl_xor(sm, 1);
    sm += __shfl_xor(sm, 2);
    sm += __shfl_xor(sm, 4);
    sm += __shfl_xor(sm, 8);
    ev[r] = e;
    rinv[r] = 1.0f / sm;
  }

  // ---- P -> LDS [h][g] (bf16), read back as A-frag ----
  u16* pw = pb[wave];
  #pragma unroll
  for (int r = 0; r < 4; ++r)
    pw[(quad * 4 + r) * 16 + l15] = f2bf(ev[r]);

  short8 pa = (short8){0, 0, 0, 0, 0, 0, 0, 0};
  if (quad < 2)                                // k = quad*8+j < 16 real, rest zero
    pa = *(const short8*)(pw + l15 * 16 + quad * 8);

  // ---- PV: out[h][d] = sum_g P[h][g] V[g][d] ----
  f32x4 o[4];
  #pragma unroll
  for (int nt = 0; nt < 4; ++nt) o[nt] = (f32x4){0.f, 0.f, 0.f, 0.f};
  #pragma unroll
  for (int nt = 0; nt < 4; ++nt) {
    short8 vf = (short8){0, 0, 0, 0, 0, 0, 0, 0};
    if (quad < 2) {
      #pragma unroll
      for (int j = 0; j < 8; ++j)
        vf[j] = (short)vb[(quad * 8 + j) * 64 + nt * 16 + l15];
    }
    o[nt] = __builtin_amdgcn_mfma_f32_16x16x32_bf16(pa, vf, o[nt], 0, 0, 0);
  }

  // ---- write: lane holds O[h=quad*4+r][d=nt*16+l15] ----
  u16* aop = ao + (size_t)t * 1024;
  #pragma unroll
  for (int nt = 0; nt < 4; ++nt)
    #pragma unroll
    for (int r = 0; r < 4; ++r)
      aop[(quad * 4 + r) * 64 + nt * 16 + l15] = f2bf(o[nt][r] * rinv[r]);
}

// ---------------- LayerNorm over E=1024 (one row per block) ----------------
template<int F32OUT>
__global__ __launch_bounds__(256)
void ln_k(const u16* __restrict__ s, const float* __restrict__ gw,
          const float* __restrict__ bw, void* __restrict__ outp) {
  const int row = blockIdx.x;
  const int tid = threadIdx.x;
  const uint2 u = ((const uint2*)(s + (size_t)row * 1024))[tid];
  const float v0 = __uint_as_float(u.x << 16);
  const float v1 = __uint_as_float(u.x & 0xFFFF0000u);
  const float v2 = __uint_as_float(u.y << 16);
  const float v3 = __uint_as_float(u.y & 0xFFFF0000u);
  float sum = v0 + v1 + v2 + v3;
  float sq  = v0 * v0 + v1 * v1 + v2 * v2 + v3 * v3;
  #pragma unroll
  for (int off = 32; off >= 1; off >>= 1) {
    sum += __shfl_xor(sum, off);
    sq  += __shfl_xor(sq, off);
  }
  __shared__ float red[8];
  const int wave = tid >> 6;
  if ((tid & 63) == 0) { red[wave] = sum; red[4 + wave] = sq; }
  __syncthreads();
  sum = red[0] + red[1] + red[2] + red[3];
  sq  = red[4] + red[5] + red[6] + red[7];
  const float mu   = sum * (1.0f / 1024.0f);
  const float rstd = rsqrtf(sq * (1.0f / 1024.0f) - mu * mu + 1e-5f);
  const float4 g4 = ((const float4*)gw)[tid];
  const float4 b4 = ((const float4*)bw)[tid];
  const float o0 = (v0 - mu) * rstd * g4.x + b4.x;
  const float o1 = (v1 - mu) * rstd * g4.y + b4.y;
  const float o2 = (v2 - mu) * rstd * g4.z + b4.z;
  const float o3 = (v3 - mu) * rstd * g4.w + b4.w;
  if (F32OUT) {
    ((float4*)outp)[(size_t)row * 256 + tid] = make_float4(o0, o1, o2, o3);
  } else {
    ((uint2*)outp)[(size_t)row * 256 + tid] = make_uint2(pack2(o0, o1), pack2(o2, o3));
  }
}

extern "C" void kernel_launch(void* const* d_in, const int* in_sizes, int n_in,
                              void* d_out, int out_size, void* d_ws, size_t ws_size,
                              hipStream_t stream) {
  const float* x      = (const float*)d_in[0];
  const float* qk_w   = (const float*)d_in[1];
  const float* qk_b   = (const float*)d_in[2];
  const float* v_w    = (const float*)d_in[3];
  const float* v_b    = (const float*)d_in[4];
  const float* proj_w = (const float*)d_in[5];
  const float* proj_b = (const float*)d_in[6];
  const float* ff_w   = (const float*)d_in[7];
  const float* ff_b   = (const float*)d_in[8];
  const float* ln_g   = (const float*)d_in[9];
  const float* ln_b   = (const float*)d_in[10];

  char* ws = (char*)d_ws;
  u16*   wqkv    = (u16*)(ws);                       //  6,291,456 B
  u16*   wproj   = (u16*)(ws + 6291456);             //  2,097,152 B
  u16*   wff     = (u16*)(ws + 8388608);             //  2,097,152 B
  float* qkvbias = (float*)(ws + 10485760);          //     12,288 B
  u16*   qkv     = (u16*)(ws + 10498048);            // 201,326,592 B (dead after attn)
  u16*   s1      = qkv;                              // alias: proj out (64MB)
  u16*   s2      = (u16*)(ws + 10498048 + 67108864); // alias: ff out (64MB, in qkv region)
  u16*   ao      = (u16*)(ws + 211824640);           //  67,108,864 B (dead after proj)
  u16*   h1      = ao;                               // alias: ln1 out
  u16*   xb      = (u16*)(ws + 278933504);           //  67,108,864 B (LIVE: residual both GEMMs)

  cast_all_k<<<37888, 256, 0, stream>>>(
      (const float4*)x,
      (const float4*)qk_w, (const float4*)v_w, (const float4*)proj_w, (const float4*)ff_w,
      (const float4*)qk_b, (const float4*)v_b,
      (uint2*)xb, (uint2*)wqkv, (uint2*)wproj, (uint2*)wff, (float4*)qkvbias);

  dim3 gqkv(NQKV / 256, M_TOK / 256);
  gemm_bt<0><<<gqkv, 512, 0, stream>>>(xb, wqkv, qkvbias, nullptr, qkv, M_TOK, NQKV, E_DIM);

  attn_k<<<M_TOK / 4, 256, 0, stream>>>(qkv, ao);

  dim3 gsq(E_DIM / 256, M_TOK / 256);
  gemm_bt<1><<<gsq, 512, 0, stream>>>(ao, wproj, proj_b, xb, s1, M_TOK, E_DIM, E_DIM);

  ln_k<0><<<M_TOK, 256, 0, stream>>>(s1, ln_g, ln_b, h1);

  gemm_bt<2><<<gsq, 512, 0, stream>>>(h1, wff, ff_b, xb, s2, M_TOK, E_DIM, E_DIM);

  ln_k<1><<<M_TOK, 256, 0, stream>>>(s2, ln_g, ln_b, d_out);
}

// Round 6
// 837.040 us; speedup vs baseline: 1.1494x; 1.1494x over previous
//
#include <hip/hip_runtime.h>
#include <cstdint>
#include <cstddef>

typedef unsigned short u16;
typedef unsigned int   u32;

using short8 = __attribute__((ext_vector_type(8))) short;
using f32x4  = __attribute__((ext_vector_type(4))) float;

#define M_TOK 32768
#define E_DIM 1024
#define NQKV  3072

__device__ __forceinline__ u16 f2bf(float f) {
  u32 u = __float_as_uint(f);
  u += 0x7FFFu + ((u >> 16) & 1u);
  return (u16)(u >> 16);
}
__device__ __forceinline__ float bf2f(u16 v) {
  return __uint_as_float((u32)v << 16);
}
__device__ __forceinline__ u32 pack2(float a, float b) {
  return (u32)f2bf(a) | ((u32)f2bf(b) << 16);
}

__device__ __forceinline__ void gl_lds16(const void* g, void* l) {
  __builtin_amdgcn_global_load_lds(
      (const __attribute__((address_space(1))) u32*)g,
      (__attribute__((address_space(3))) u32*)l, 16, 0, 0);
}

// ---------------- combined cast: x + all weights + qkv bias ----------------
__global__ __launch_bounds__(256) void cast_all_k(
    const float4* __restrict__ x,
    const float4* __restrict__ qkw, const float4* __restrict__ vw,
    const float4* __restrict__ pw,  const float4* __restrict__ fw,
    const float4* __restrict__ qkb, const float4* __restrict__ vb,
    uint2* __restrict__ xb,
    uint2* __restrict__ wqkv, uint2* __restrict__ wproj, uint2* __restrict__ wff,
    float4* __restrict__ qkvbias) {
  const int gid = blockIdx.x * 256 + threadIdx.x;   // 9,699,328 total
  if (gid < 8388608) {
    const float4 v = x[gid];
    xb[gid] = make_uint2(pack2(v.x, v.y), pack2(v.z, v.w));
    return;
  }
  const int w = gid - 8388608;                      // [0, 1,310,720)
  float4 v; uint2* dst; int di;
  if (w < 524288)        { v = qkw[w];           dst = wqkv;  di = w; }
  else if (w < 786432)   { v = vw[w - 524288];   dst = wqkv;  di = w; }
  else if (w < 1048576)  { v = pw[w - 786432];   dst = wproj; di = w - 786432; }
  else                   { v = fw[w - 1048576];  dst = wff;   di = w - 1048576; }
  dst[di] = make_uint2(pack2(v.x, v.y), pack2(v.z, v.w));
  if (w < 768) qkvbias[w] = (w < 512) ? qkb[w] : vb[w - 512];
}

// ---------------- GEMM: C[M,N] = A[M,K] @ Bw[N,K]^T (+bias, +epilogue) ----------------
// MODE 0: C=bf16(acc+bias)                 (qkv)
// MODE 1: C=bf16(acc+bias+xres)            (proj + residual, xres bf16)
// MODE 2: C=bf16(gelu(acc+bias)+xres)      (ff + gelu + residual, xres bf16)
//
// R6: 128x256 tile, 512 threads = 8 waves (2M x 4N), single 48KB LDS buffer,
// 2 blocks/CU (16 waves). Per-wave compute path is BYTE-IDENTICAL to the
// proven 128^2 baseline (4x4 acc of 16x16x32, same XOR-swizzle reads);
// only staging constants / grid change. Rationale: R3/R4 showed GEMM time
// == LDS byte-delivery service time; this tile stages 24 B/output vs 32
// (-25%) while keeping multi-block TLP (the 256^2 1-blk/CU shape lost to
// latency exposure despite 16 B/output).
// __launch_bounds__(512,4) caps VGPR at 128 (= baseline's natural count)
// to guarantee 2-block residency.
template<int MODE>
__global__ __launch_bounds__(512, 4)
void gemm_bt(const u16* __restrict__ A, const u16* __restrict__ Bw,
             const float* __restrict__ bias, const u16* __restrict__ xres,
             u16* __restrict__ C, int M, int N, int K) {
  __shared__ __align__(16) u16 As[128 * 64];
  __shared__ __align__(16) u16 Bs[256 * 64];
  const int tid  = threadIdx.x;
  const int lane = tid & 63;
  const int wave = tid >> 6;
  const int wm = wave & 1;       // 2 waves in M (128 rows)
  const int wn = wave >> 1;      // 4 waves in N (256 cols)
  const int quad = lane >> 4;
  const int l15  = lane & 15;
  const int row0 = blockIdx.y * 128;
  const int col0 = blockIdx.x * 256;

  f32x4 acc[4][4];
  #pragma unroll
  for (int i = 0; i < 4; ++i)
    #pragma unroll
    for (int j = 0; j < 4; ++j)
      acc[i][j] = (f32x4){0.f, 0.f, 0.f, 0.f};

  // DMA mapping (512 threads): per call, chunk L = c*512 + tid (16B chunks);
  // row ml = L>>3 (64 rows/call), slot cp = tid&7.
  // XOR swizzle: LDS slot (ml, cp) holds global k-chunk cp ^ (ml&7);
  // c*64 ≡ 0 mod 8 keeps gch invariant in c.
  const int ml_t = tid >> 3;                 // 0..63, + c*64 per call
  const int gch  = (tid & 7) ^ (ml_t & 7);
  const u16* srcA0 = A  + (size_t)(row0 + ml_t) * K + gch * 8;
  const u16* srcB0 = Bw + (size_t)(col0 + ml_t) * K + gch * 8;
  const int ldsbase = wave * 512;            // elements (64 lanes x 16B)

  const int nkt = K >> 6;
  for (int kt = 0; kt < nkt; ++kt) {
    const int k0 = kt << 6;
    __syncthreads();
    // A: 2 slabs x 64 rows
    gl_lds16(srcA0 + k0,                     As + ldsbase);
    gl_lds16(srcA0 + k0 + (size_t)64 * K,    As + ldsbase + 4096);
    // B: 4 slabs x 64 rows
    #pragma unroll
    for (int c = 0; c < 4; ++c)
      gl_lds16(srcB0 + k0 + (size_t)c * 64 * K, Bs + ldsbase + c * 4096);
    __syncthreads();
    #pragma unroll
    for (int kk = 0; kk < 2; ++kk) {
      const int cidx = (kk << 2) + quad;
      short8 af[4], bfr[4];
      #pragma unroll
      for (int i = 0; i < 4; ++i) {
        const int m = wm * 64 + i * 16 + l15;
        af[i]  = *(const short8*)(As + (m * 8 + (cidx ^ (m & 7))) * 8);
        const int n = wn * 64 + i * 16 + l15;
        bfr[i] = *(const short8*)(Bs + (n * 8 + (cidx ^ (n & 7))) * 8);
      }
      #pragma unroll
      for (int i = 0; i < 4; ++i)
        #pragma unroll
        for (int j = 0; j < 4; ++j)
          acc[i][j] = __builtin_amdgcn_mfma_f32_16x16x32_bf16(af[i], bfr[j], acc[i][j], 0, 0, 0);
    }
  }

  #pragma unroll
  for (int j = 0; j < 4; ++j) {
    const int col = col0 + wn * 64 + j * 16 + l15;
    const float bj = bias[col];
    #pragma unroll
    for (int i = 0; i < 4; ++i) {
      const int rowb = row0 + wm * 64 + i * 16 + quad * 4;
      #pragma unroll
      for (int r = 0; r < 4; ++r) {
        const int row = rowb + r;
        float v = acc[i][j][r] + bj;
        if (MODE == 1) {
          v += bf2f(xres[(size_t)row * N + col]);
        } else if (MODE == 2) {
          v = 0.5f * v * (1.0f + erff(v * 0.70710678118654752f))
              + bf2f(xres[(size_t)row * N + col]);
        }
        C[(size_t)row * N + col] = f2bf(v);
      }
    }
  }
}

// ---------------- per-token head-mixing attention (MFMA, 1 wave = 1 token) ----------------
__global__ __launch_bounds__(256)
void attn_k(const u16* __restrict__ qkv, u16* __restrict__ ao) {
  __shared__ __align__(16) u16 pb[4][256];
  const int tid  = threadIdx.x;
  const int wave = tid >> 6;
  const int lane = tid & 63;
  const int quad = lane >> 4;
  const int l15  = lane & 15;
  const int t = blockIdx.x * 4 + wave;
  const u16* base = qkv + (size_t)t * 3072;
  const u16* qb = base;
  const u16* kb = base + 1024;
  const u16* vb = base + 2048;

  // ---- QK^T ----
  const int fo = l15 * 64 + quad * 8;          // frag: m/n = l15, k = quad*8+j
  const short8 a0 = *(const short8*)(qb + fo);
  const short8 a1 = *(const short8*)(qb + fo + 32);
  const short8 b0 = *(const short8*)(kb + fo);
  const short8 b1 = *(const short8*)(kb + fo + 32);
  f32x4 s = (f32x4){0.f, 0.f, 0.f, 0.f};
  s = __builtin_amdgcn_mfma_f32_16x16x32_bf16(a0, b0, s, 0, 0, 0);
  s = __builtin_amdgcn_mfma_f32_16x16x32_bf16(a1, b1, s, 0, 0, 0);
  // lane holds S[h=quad*4+r][g=l15]

  // ---- softmax over g (16-lane groups share quad) ----
  float rinv[4];
  float ev[4];
  #pragma unroll
  for (int r = 0; r < 4; ++r) {
    float sv = s[r] * 0.125f;
    float m = sv;
    m = fmaxf(m, __shfl_xor(m, 1));
    m = fmaxf(m, __shfl_xor(m, 2));
    m = fmaxf(m, __shfl_xor(m, 4));
    m = fmaxf(m, __shfl_xor(m, 8));
    const float e = __expf(sv - m);
    float sm = e;
    sm += __shfl_xor(sm, 1);
    sm += __shfl_xor(sm, 2);
    sm += __shfl_xor(sm, 4);
    sm += __shfl_xor(sm, 8);
    ev[r] = e;
    rinv[r] = 1.0f / sm;
  }

  // ---- P -> LDS [h][g] (bf16), read back as A-frag ----
  u16* pw = pb[wave];
  #pragma unroll
  for (int r = 0; r < 4; ++r)
    pw[(quad * 4 + r) * 16 + l15] = f2bf(ev[r]);

  short8 pa = (short8){0, 0, 0, 0, 0, 0, 0, 0};
  if (quad < 2)                                // k = quad*8+j < 16 real, rest zero
    pa = *(const short8*)(pw + l15 * 16 + quad * 8);

  // ---- PV: out[h][d] = sum_g P[h][g] V[g][d] ----
  f32x4 o[4];
  #pragma unroll
  for (int nt = 0; nt < 4; ++nt) o[nt] = (f32x4){0.f, 0.f, 0.f, 0.f};
  #pragma unroll
  for (int nt = 0; nt < 4; ++nt) {
    short8 vf = (short8){0, 0, 0, 0, 0, 0, 0, 0};
    if (quad < 2) {
      #pragma unroll
      for (int j = 0; j < 8; ++j)
        vf[j] = (short)vb[(quad * 8 + j) * 64 + nt * 16 + l15];
    }
    o[nt] = __builtin_amdgcn_mfma_f32_16x16x32_bf16(pa, vf, o[nt], 0, 0, 0);
  }

  // ---- write: lane holds O[h=quad*4+r][d=nt*16+l15] ----
  u16* aop = ao + (size_t)t * 1024;
  #pragma unroll
  for (int nt = 0; nt < 4; ++nt)
    #pragma unroll
    for (int r = 0; r < 4; ++r)
      aop[(quad * 4 + r) * 64 + nt * 16 + l15] = f2bf(o[nt][r] * rinv[r]);
}

// ---------------- LayerNorm over E=1024 (one row per block) ----------------
template<int F32OUT>
__global__ __launch_bounds__(256)
void ln_k(const u16* __restrict__ s, const float* __restrict__ gw,
          const float* __restrict__ bw, void* __restrict__ outp) {
  const int row = blockIdx.x;
  const int tid = threadIdx.x;
  const uint2 u = ((const uint2*)(s + (size_t)row * 1024))[tid];
  const float v0 = __uint_as_float(u.x << 16);
  const float v1 = __uint_as_float(u.x & 0xFFFF0000u);
  const float v2 = __uint_as_float(u.y << 16);
  const float v3 = __uint_as_float(u.y & 0xFFFF0000u);
  float sum = v0 + v1 + v2 + v3;
  float sq  = v0 * v0 + v1 * v1 + v2 * v2 + v3 * v3;
  #pragma unroll
  for (int off = 32; off >= 1; off >>= 1) {
    sum += __shfl_xor(sum, off);
    sq  += __shfl_xor(sq, off);
  }
  __shared__ float red[8];
  const int wave = tid >> 6;
  if ((tid & 63) == 0) { red[wave] = sum; red[4 + wave] = sq; }
  __syncthreads();
  sum = red[0] + red[1] + red[2] + red[3];
  sq  = red[4] + red[5] + red[6] + red[7];
  const float mu   = sum * (1.0f / 1024.0f);
  const float rstd = rsqrtf(sq * (1.0f / 1024.0f) - mu * mu + 1e-5f);
  const float4 g4 = ((const float4*)gw)[tid];
  const float4 b4 = ((const float4*)bw)[tid];
  const float o0 = (v0 - mu) * rstd * g4.x + b4.x;
  const float o1 = (v1 - mu) * rstd * g4.y + b4.y;
  const float o2 = (v2 - mu) * rstd * g4.z + b4.z;
  const float o3 = (v3 - mu) * rstd * g4.w + b4.w;
  if (F32OUT) {
    ((float4*)outp)[(size_t)row * 256 + tid] = make_float4(o0, o1, o2, o3);
  } else {
    ((uint2*)outp)[(size_t)row * 256 + tid] = make_uint2(pack2(o0, o1), pack2(o2, o3));
  }
}

extern "C" void kernel_launch(void* const* d_in, const int* in_sizes, int n_in,
                              void* d_out, int out_size, void* d_ws, size_t ws_size,
                              hipStream_t stream) {
  const float* x      = (const float*)d_in[0];
  const float* qk_w   = (const float*)d_in[1];
  const float* qk_b   = (const float*)d_in[2];
  const float* v_w    = (const float*)d_in[3];
  const float* v_b    = (const float*)d_in[4];
  const float* proj_w = (const float*)d_in[5];
  const float* proj_b = (const float*)d_in[6];
  const float* ff_w   = (const float*)d_in[7];
  const float* ff_b   = (const float*)d_in[8];
  const float* ln_g   = (const float*)d_in[9];
  const float* ln_b   = (const float*)d_in[10];

  char* ws = (char*)d_ws;
  u16*   wqkv    = (u16*)(ws);                       //  6,291,456 B
  u16*   wproj   = (u16*)(ws + 6291456);             //  2,097,152 B
  u16*   wff     = (u16*)(ws + 8388608);             //  2,097,152 B
  float* qkvbias = (float*)(ws + 10485760);          //     12,288 B
  u16*   qkv     = (u16*)(ws + 10498048);            // 201,326,592 B (dead after attn)
  u16*   s1      = qkv;                              // alias: proj out (64MB)
  u16*   s2      = (u16*)(ws + 10498048 + 67108864); // alias: ff out (64MB, in qkv region)
  u16*   ao      = (u16*)(ws + 211824640);           //  67,108,864 B (dead after proj)
  u16*   h1      = ao;                               // alias: ln1 out
  u16*   xb      = (u16*)(ws + 278933504);           //  67,108,864 B (LIVE: residual both GEMMs)

  cast_all_k<<<37888, 256, 0, stream>>>(
      (const float4*)x,
      (const float4*)qk_w, (const float4*)v_w, (const float4*)proj_w, (const float4*)ff_w,
      (const float4*)qk_b, (const float4*)v_b,
      (uint2*)xb, (uint2*)wqkv, (uint2*)wproj, (uint2*)wff, (float4*)qkvbias);

  dim3 gqkv(NQKV / 256, M_TOK / 128);
  gemm_bt<0><<<gqkv, 512, 0, stream>>>(xb, wqkv, qkvbias, nullptr, qkv, M_TOK, NQKV, E_DIM);

  attn_k<<<M_TOK / 4, 256, 0, stream>>>(qkv, ao);

  dim3 gsq(E_DIM / 256, M_TOK / 128);
  gemm_bt<1><<<gsq, 512, 0, stream>>>(ao, wproj, proj_b, xb, s1, M_TOK, E_DIM, E_DIM);

  ln_k<0><<<M_TOK, 256, 0, stream>>>(s1, ln_g, ln_b, h1);

  gemm_bt<2><<<gsq, 512, 0, stream>>>(h1, wff, ff_b, xb, s2, M_TOK, E_DIM, E_DIM);

  ln_k<1><<<M_TOK, 256, 0, stream>>>(s2, ln_g, ln_b, d_out);
}